// Round 5
// baseline (951.272 us; speedup 1.0000x reference)
//
#include <hip/hip_runtime.h>

#define TPB 256
#define BSH 5                    // 32 dst nodes per bucket
#define BNODES 32
#define CAP 1024                 // slots per bucket; Poisson(512), 22-sigma margin

// ---------------- bucket build ----------------

__global__ void k_zero(int* __restrict__ a, int n) {
    int i = blockIdx.x * TPB + threadIdx.x;
    if (i < n) a[i] = 0;
}

// scatter each edge into its dst-bucket as packed (src<<5 | dstLocal)
__global__ void k_bfill(const int* __restrict__ src, const int* __restrict__ dst,
                        int* __restrict__ bcnt, unsigned* __restrict__ ebuf, int E) {
    int e = blockIdx.x * TPB + threadIdx.x;
    if (e < E) {
        int d = dst[e];
        int b = d >> BSH;
        int pos = atomicAdd(&bcnt[b], 1);
        if (pos < CAP) {
            unsigned pk = ((unsigned)src[e] << BSH) | (unsigned)(d & (BNODES - 1));
            ebuf[(size_t)b * CAP + pos] = pk;
        }
    }
}

// per-bucket degree via LDS atomics -> dinv = rsqrt(deg+1); 8 buckets per wg
__global__ void k_bdeg(const int* __restrict__ bcnt, const unsigned* __restrict__ ebuf,
                       float* __restrict__ dinv, int nb, int n) {
    __shared__ int sdeg[256];
    sdeg[threadIdx.x] = 0;
    __syncthreads();
    int b0 = blockIdx.x * 8;
    for (int j = 0; j < 8; ++j) {
        int b = b0 + j;
        if (b >= nb) break;
        int cnt = bcnt[b];
        if (cnt > CAP) cnt = CAP;
        const unsigned* p = &ebuf[(size_t)b * CAP];
        for (int k = threadIdx.x; k < cnt; k += TPB)
            atomicAdd(&sdeg[(j << BSH) | (p[k] & (BNODES - 1))], 1);
    }
    __syncthreads();
    int node = blockIdx.x * 256 + threadIdx.x;
    if (node < n) dinv[node] = rsqrtf((float)sdeg[threadIdx.x] + 1.0f);
}

// ---------------- dense transforms (pre-scaled by dinv[row], fp16 out) ------

// g[row,:] = fp16( dinv[row] * (x[row,:] @ W[64,64]) ); 4 rows/block
__global__ void k_xw64s(const float* __restrict__ x, const float* __restrict__ W,
                        const float* __restrict__ dinv, _Float16* __restrict__ g, int n) {
    __shared__ float Ws[64 * 64];
    __shared__ float xs[4][64];
    int tid = threadIdx.x;
    for (int i = tid; i < 64 * 64; i += TPB) Ws[i] = W[i];
    int r = tid >> 6, c = tid & 63;
    int row = blockIdx.x * 4 + r;
    if (row < n) xs[r][c] = x[(size_t)row * 64 + c];
    __syncthreads();
    if (row < n) {
        float acc = 0.f;
#pragma unroll
        for (int k = 0; k < 64; ++k) acc += xs[r][k] * Ws[k * 64 + c];
        g[(size_t)row * 64 + c] = (_Float16)(dinv[row] * acc);
    }
}

// g2[row,:19] = fp16( dinv[row] * (h[row,:] @ W2[64,19]) ); 8 rows/block; h fp16
__global__ void k_xw19s(const _Float16* __restrict__ h, const float* __restrict__ W,
                        const float* __restrict__ dinv, _Float16* __restrict__ g2, int n) {
    __shared__ float Ws[64][20];
    __shared__ float xs[8][64];
    int tid = threadIdx.x;
    for (int i = tid; i < 64 * 19; i += TPB) Ws[i / 19][i % 19] = W[i];
    for (int i = tid; i < 8 * 64; i += TPB) {
        int rr = i >> 6, cc = i & 63;
        int row = blockIdx.x * 8 + rr;
        if (row < n) xs[rr][cc] = (float)h[(size_t)row * 64 + cc];
    }
    __syncthreads();
    int r = tid >> 5, c = tid & 31;
    int row = blockIdx.x * 8 + r;
    if (row < n && c < 19) {
        float acc = 0.f;
#pragma unroll
        for (int k = 0; k < 64; ++k) acc += xs[r][k] * Ws[k][c];
        g2[(size_t)row * 19 + c] = (_Float16)(dinv[row] * acc);
    }
}

// ---------------- bucketed aggregation (LDS tile, no global atomics) --------

// one wg per bucket; acc[32][64] fp32 in LDS; 4 waves stream the edge list
__global__ void k_bagg64(const int* __restrict__ bcnt, const unsigned* __restrict__ ebuf,
                         const float* __restrict__ dinv, const _Float16* __restrict__ g,
                         const float* __restrict__ b1, _Float16* __restrict__ h, int n) {
    __shared__ float acc[BNODES][64];
    int tid = threadIdx.x, lane = tid & 63, wv = tid >> 6;
    for (int i = tid; i < BNODES * 64; i += TPB) ((float*)acc)[i] = 0.f;
    __syncthreads();
    int b = blockIdx.x;
    int cnt = bcnt[b];
    if (cnt > CAP) cnt = CAP;
    const unsigned* p = &ebuf[(size_t)b * CAP];
    int per = (cnt + 3) >> 2;
    int k0 = wv * per, k1 = k0 + per;
    if (k1 > cnt) k1 = cnt;
    int k = k0;
    for (; k + 3 < k1; k += 4) {
        unsigned p0 = p[k], p1 = p[k + 1], p2 = p[k + 2], p3 = p[k + 3];
        float v0 = (float)g[(size_t)(p0 >> BSH) * 64 + lane];
        float v1 = (float)g[(size_t)(p1 >> BSH) * 64 + lane];
        float v2 = (float)g[(size_t)(p2 >> BSH) * 64 + lane];
        float v3 = (float)g[(size_t)(p3 >> BSH) * 64 + lane];
        atomicAdd(&acc[p0 & (BNODES - 1)][lane], v0);
        atomicAdd(&acc[p1 & (BNODES - 1)][lane], v1);
        atomicAdd(&acc[p2 & (BNODES - 1)][lane], v2);
        atomicAdd(&acc[p3 & (BNODES - 1)][lane], v3);
    }
    for (; k < k1; ++k) {
        unsigned pk = p[k];
        atomicAdd(&acc[pk & (BNODES - 1)][lane], (float)g[(size_t)(pk >> BSH) * 64 + lane]);
    }
    __syncthreads();
    int node0 = b * BNODES;
    for (int r = wv; r < BNODES; r += 4) {
        int node = node0 + r;
        if (node >= n) break;
        float v = dinv[node] * (acc[r][lane] + (float)g[(size_t)node * 64 + lane]) + b1[lane];
        h[(size_t)node * 64 + lane] = (_Float16)fmaxf(v, 0.f);
    }
}

// one wg per bucket; acc[32][20] fp32; 2 edges per wave-iter (lanes 0-18, 32-50)
__global__ void k_bagg19(const int* __restrict__ bcnt, const unsigned* __restrict__ ebuf,
                         const float* __restrict__ dinv, const _Float16* __restrict__ g2,
                         const float* __restrict__ b2, float* __restrict__ out, int n) {
    __shared__ float acc[BNODES][20];
    int tid = threadIdx.x, lane = tid & 63, wv = tid >> 6;
    for (int i = tid; i < BNODES * 20; i += TPB) ((float*)acc)[i] = 0.f;
    __syncthreads();
    int b = blockIdx.x;
    int cnt = bcnt[b];
    if (cnt > CAP) cnt = CAP;
    const unsigned* p = &ebuf[(size_t)b * CAP];
    int half = lane >> 5, c = lane & 31;
    int per = (cnt + 3) >> 2;
    int k0 = wv * per, k1 = k0 + per;
    if (k1 > cnt) k1 = cnt;
    for (int k = k0; k < k1; k += 4) {
        int ka = k + half, kb = k + 2 + half;
        if (c < 19) {
            if (ka < k1) {
                unsigned pk = p[ka];
                atomicAdd(&acc[pk & (BNODES - 1)][c], (float)g2[(size_t)(pk >> BSH) * 19 + c]);
            }
            if (kb < k1) {
                unsigned pk = p[kb];
                atomicAdd(&acc[pk & (BNODES - 1)][c], (float)g2[(size_t)(pk >> BSH) * 19 + c]);
            }
        }
    }
    __syncthreads();
    for (int i = tid; i < BNODES * 19; i += TPB) {
        int r = i / 19, cc = i - r * 19;
        int node = b * BNODES + r;
        if (node < n) {
            float v = dinv[node] * (acc[r][cc] + (float)g2[(size_t)node * 19 + cc]) + b2[cc];
            out[(size_t)node * 19 + cc] = v;
        }
    }
}

// ---------------- launch ----------------

extern "C" void kernel_launch(void* const* d_in, const int* in_sizes, int n_in,
                              void* d_out, int out_size, void* d_ws, size_t ws_size,
                              hipStream_t stream) {
    const float* x  = (const float*)d_in[0];
    const int*   ei = (const int*)d_in[1];
    const float* W1 = (const float*)d_in[2];
    const float* b1 = (const float*)d_in[3];
    const float* W2 = (const float*)d_in[4];
    const float* b2 = (const float*)d_in[5];
    float* out = (float*)d_out;

    int N = in_sizes[0] / 64;
    int E = in_sizes[1] / 2;
    const int* src = ei;
    const int* dst = ei + E;

    int NB = (N + BNODES - 1) >> BSH;   // 3125 for N=100000

    char* w = (char*)d_ws;
    int* bcnt       = (int*)w;      w += (size_t)NB * 4;
    float* dinv     = (float*)w;    w += (size_t)N * 4;
    w = (char*)(((size_t)w + 63) & ~(size_t)63);
    unsigned* ebuf  = (unsigned*)w; w += (size_t)NB * CAP * 4;
    _Float16* g1    = (_Float16*)w; w += (size_t)N * 64 * 2;
    _Float16* h     = (_Float16*)w; w += (size_t)N * 64 * 2;
    _Float16* g2    = g1;  // g1 dead after k_bagg64; reuse

    int gE = (E + TPB - 1) / TPB;

    k_zero  <<<(NB + TPB - 1) / TPB, TPB, 0, stream>>>(bcnt, NB);
    k_bfill <<<gE, TPB, 0, stream>>>(src, dst, bcnt, ebuf, E);
    k_bdeg  <<<(NB + 7) / 8, TPB, 0, stream>>>(bcnt, ebuf, dinv, NB, N);

    k_xw64s <<<(N + 3) / 4, TPB, 0, stream>>>(x, W1, dinv, g1, N);
    k_bagg64<<<NB, TPB, 0, stream>>>(bcnt, ebuf, dinv, g1, b1, h, N);

    k_xw19s <<<(N + 7) / 8, TPB, 0, stream>>>(h, W2, dinv, g2, N);
    k_bagg19<<<NB, TPB, 0, stream>>>(bcnt, ebuf, dinv, g2, b2, out, N);
}

// Round 6
// 332.245 us; speedup vs baseline: 2.8632x; 2.8632x over previous
//
#include <hip/hip_runtime.h>

#define TPB 256
#define BSH 5                    // 32 dst nodes per bucket
#define BNODES 32
#define CAP 1024                 // slots per bucket; mean 512, huge tail margin

// ---------------- bucket build ----------------

__global__ void k_zero(int* __restrict__ a, int n) {
    int i = blockIdx.x * TPB + threadIdx.x;
    if (i < n) a[i] = 0;
}

// scatter each edge into its dst-bucket as packed (src<<5 | dstLocal)
__global__ void k_bfill(const int* __restrict__ src, const int* __restrict__ dst,
                        int* __restrict__ bcnt, unsigned* __restrict__ ebuf, int E) {
    int e = blockIdx.x * TPB + threadIdx.x;
    if (e < E) {
        int d = dst[e];
        int b = d >> BSH;
        int pos = atomicAdd(&bcnt[b], 1);   // int atomic: native HW RMW
        if (pos < CAP) {
            unsigned pk = ((unsigned)src[e] << BSH) | (unsigned)(d & (BNODES - 1));
            ebuf[(size_t)b * CAP + pos] = pk;
        }
    }
}

// one WAVE per bucket: LDS-stage edges, int-LDS histogram, shfl-scan,
// scatter into padded CSR; emit deg / node_beg / dinv. No float atomics.
__global__ void k_bcsr(const int* __restrict__ bcnt, const unsigned* __restrict__ ebuf,
                       int* __restrict__ csr, int* __restrict__ node_beg,
                       int* __restrict__ degi, float* __restrict__ dinv, int nb, int n) {
    __shared__ unsigned se[4][CAP];        // 16 KB edge stage
    __shared__ int scnt[4][BNODES];        // histogram
    __shared__ int sexc[4][BNODES];        // exclusive offsets
    __shared__ int srnk[4][BNODES];        // rank counters
    int wv = threadIdx.x >> 6, lane = threadIdx.x & 63;
    int b = blockIdx.x * 4 + wv;
    bool act = (b < nb);
    int cnt = 0;
    const unsigned* p = nullptr;
    if (act) {
        cnt = bcnt[b];
        if (cnt > CAP) cnt = CAP;
        p = &ebuf[(size_t)b * CAP];
    }
    if (lane < BNODES) { scnt[wv][lane] = 0; srnk[wv][lane] = 0; }
    __syncthreads();
    if (act) {
        for (int k = lane; k < cnt; k += 64) {
            unsigned pk = p[k];
            se[wv][k] = pk;
            atomicAdd(&scnt[wv][pk & (BNODES - 1)], 1);   // int LDS atomic: native
        }
    }
    __syncthreads();
    if (act && lane < BNODES) {
        int deg = scnt[wv][lane];
        int v = deg;
#pragma unroll
        for (int off = 1; off < BNODES; off <<= 1) {
            int t = __shfl_up(v, off, BNODES);
            if (lane >= off) v += t;
        }
        int excl = v - deg;
        sexc[wv][lane] = excl;
        int node = b * BNODES + lane;
        if (node < n) {
            degi[node] = deg;
            node_beg[node] = b * CAP + excl;
            dinv[node] = rsqrtf((float)deg + 1.0f);
        }
    }
    __syncthreads();
    if (act) {
        int* csrb = csr + (size_t)b * CAP;
        for (int k = lane; k < cnt; k += 64) {
            unsigned pk = se[wv][k];
            int dl = pk & (BNODES - 1);
            int r = atomicAdd(&srnk[wv][dl], 1);          // int LDS atomic
            csrb[sexc[wv][dl] + r] = (int)(pk >> BSH);
        }
    }
}

// ---------------- dense transforms (pre-scaled by dinv[row], fp16 out) ------

// g[row,:] = fp16( dinv[row] * (x[row,:] @ W[64,64]) ); 4 rows/block
__global__ void k_xw64s(const float* __restrict__ x, const float* __restrict__ W,
                        const float* __restrict__ dinv, _Float16* __restrict__ g, int n) {
    __shared__ float Ws[64 * 64];
    __shared__ float xs[4][64];
    int tid = threadIdx.x;
    for (int i = tid; i < 64 * 64; i += TPB) Ws[i] = W[i];
    int r = tid >> 6, c = tid & 63;
    int row = blockIdx.x * 4 + r;
    if (row < n) xs[r][c] = x[(size_t)row * 64 + c];
    __syncthreads();
    if (row < n) {
        float acc = 0.f;
#pragma unroll
        for (int k = 0; k < 64; ++k) acc += xs[r][k] * Ws[k * 64 + c];
        g[(size_t)row * 64 + c] = (_Float16)(dinv[row] * acc);
    }
}

// g2[row,:19] = fp16( dinv[row] * (h[row,:] @ W2[64,19]) ); 8 rows/block; h fp16
__global__ void k_xw19s(const _Float16* __restrict__ h, const float* __restrict__ W,
                        const float* __restrict__ dinv, _Float16* __restrict__ g2, int n) {
    __shared__ float Ws[64][20];
    __shared__ float xs[8][64];
    int tid = threadIdx.x;
    for (int i = tid; i < 64 * 19; i += TPB) Ws[i / 19][i % 19] = W[i];
    for (int i = tid; i < 8 * 64; i += TPB) {
        int rr = i >> 6, cc = i & 63;
        int row = blockIdx.x * 8 + rr;
        if (row < n) xs[rr][cc] = (float)h[(size_t)row * 64 + cc];
    }
    __syncthreads();
    int r = tid >> 5, c = tid & 31;
    int row = blockIdx.x * 8 + r;
    if (row < n && c < 19) {
        float acc = 0.f;
#pragma unroll
        for (int k = 0; k < 64; ++k) acc += xs[r][k] * Ws[k][c];
        g2[(size_t)row * 19 + c] = (_Float16)(dinv[row] * acc);
    }
}

// ---------------- gather aggregation (register accumulate, no atomics) ------

// h[d,c] = fp16(relu(dinv[d]*(g[d,c] + sum_{s in in(d)} g[s,c]) + b1[c])); 1 wave/node
__global__ void k_gather64(const int* __restrict__ node_beg, const int* __restrict__ deg,
                           const int* __restrict__ csr_src, const float* __restrict__ dinv,
                           const _Float16* __restrict__ g, const float* __restrict__ b1,
                           _Float16* __restrict__ h, int n) {
    int node = blockIdx.x * 4 + (threadIdx.x >> 6);
    if (node >= n) return;
    int lane = threadIdx.x & 63;
    int beg = node_beg[node], cnt = deg[node];
    float a0 = (float)g[(size_t)node * 64 + lane];   // self-loop
    float a1 = 0.f, a2 = 0.f, a3 = 0.f;
    int k = 0;
    for (; k + 3 < cnt; k += 4) {
        int s0 = csr_src[beg + k];
        int s1 = csr_src[beg + k + 1];
        int s2 = csr_src[beg + k + 2];
        int s3 = csr_src[beg + k + 3];
        a0 += (float)g[(size_t)s0 * 64 + lane];
        a1 += (float)g[(size_t)s1 * 64 + lane];
        a2 += (float)g[(size_t)s2 * 64 + lane];
        a3 += (float)g[(size_t)s3 * 64 + lane];
    }
    for (; k < cnt; ++k) a1 += (float)g[(size_t)csr_src[beg + k] * 64 + lane];
    float v = dinv[node] * ((a0 + a1) + (a2 + a3)) + b1[lane];
    h[(size_t)node * 64 + lane] = (_Float16)fmaxf(v, 0.f);
}

// out[d,c] = dinv[d]*(g2[d,c] + sum g2[s,c]) + b2[c]; 32 lanes/node (19 active)
__global__ void k_gather19(const int* __restrict__ node_beg, const int* __restrict__ deg,
                           const int* __restrict__ csr_src, const float* __restrict__ dinv,
                           const _Float16* __restrict__ g2, const float* __restrict__ b2,
                           float* __restrict__ out, int n) {
    int node = blockIdx.x * 8 + (threadIdx.x >> 5);
    if (node >= n) return;
    int c = threadIdx.x & 31;
    if (c >= 19) return;
    int beg = node_beg[node], cnt = deg[node];
    float a0 = (float)g2[(size_t)node * 19 + c];     // self-loop
    float a1 = 0.f, a2 = 0.f, a3 = 0.f;
    int k = 0;
    for (; k + 3 < cnt; k += 4) {
        int s0 = csr_src[beg + k];
        int s1 = csr_src[beg + k + 1];
        int s2 = csr_src[beg + k + 2];
        int s3 = csr_src[beg + k + 3];
        a0 += (float)g2[(size_t)s0 * 19 + c];
        a1 += (float)g2[(size_t)s1 * 19 + c];
        a2 += (float)g2[(size_t)s2 * 19 + c];
        a3 += (float)g2[(size_t)s3 * 19 + c];
    }
    for (; k < cnt; ++k) a1 += (float)g2[(size_t)csr_src[beg + k] * 19 + c];
    out[(size_t)node * 19 + c] = dinv[node] * ((a0 + a1) + (a2 + a3)) + b2[c];
}

// ---------------- launch ----------------

extern "C" void kernel_launch(void* const* d_in, const int* in_sizes, int n_in,
                              void* d_out, int out_size, void* d_ws, size_t ws_size,
                              hipStream_t stream) {
    const float* x  = (const float*)d_in[0];
    const int*   ei = (const int*)d_in[1];
    const float* W1 = (const float*)d_in[2];
    const float* b1 = (const float*)d_in[3];
    const float* W2 = (const float*)d_in[4];
    const float* b2 = (const float*)d_in[5];
    float* out = (float*)d_out;

    int N = in_sizes[0] / 64;
    int E = in_sizes[1] / 2;
    const int* src = ei;
    const int* dst = ei + E;

    int NB = (N + BNODES - 1) >> BSH;   // 3125 for N=100000

    char* w = (char*)d_ws;
    int* bcnt      = (int*)w;      w += (size_t)NB * 4;
    int* degi      = (int*)w;      w += (size_t)N * 4;
    int* node_beg  = (int*)w;      w += (size_t)N * 4;
    float* dinv    = (float*)w;    w += (size_t)N * 4;
    w = (char*)(((size_t)w + 63) & ~(size_t)63);
    unsigned* ebuf = (unsigned*)w; w += (size_t)NB * CAP * 4;
    int* csr       = (int*)w;      w += (size_t)NB * CAP * 4;
    _Float16* g1   = (_Float16*)w; w += (size_t)N * 64 * 2;
    _Float16* h    = (_Float16*)w; w += (size_t)N * 64 * 2;
    _Float16* g2   = g1;  // g1 dead after k_gather64; reuse

    int gE = (E + TPB - 1) / TPB;

    k_zero    <<<(NB + TPB - 1) / TPB, TPB, 0, stream>>>(bcnt, NB);
    k_bfill   <<<gE, TPB, 0, stream>>>(src, dst, bcnt, ebuf, E);
    k_bcsr    <<<(NB + 3) / 4, TPB, 0, stream>>>(bcnt, ebuf, csr, node_beg, degi, dinv, NB, N);

    k_xw64s   <<<(N + 3) / 4, TPB, 0, stream>>>(x, W1, dinv, g1, N);
    k_gather64<<<(N + 3) / 4, TPB, 0, stream>>>(node_beg, degi, csr, dinv, g1, b1, h, N);

    k_xw19s   <<<(N + 7) / 8, TPB, 0, stream>>>(h, W2, dinv, g2, N);
    k_gather19<<<(N + 7) / 8, TPB, 0, stream>>>(node_beg, degi, csr, dinv, g2, b2, out, N);
}

// Round 7
// 259.490 us; speedup vs baseline: 3.6659x; 1.2804x over previous
//
#include <hip/hip_runtime.h>

#define TPB 256
#define BSH 5                    // 32 dst nodes per bucket
#define BNODES 32
#define CAP 1024                 // staged edges per bucket (mean 512, 22-sigma)
#define NSTRIPE 8                // one stripe per XCD (blockIdx & 7 ~ XCD id)
#define SCAP 192                 // slots per stripe-bucket (mean 64, 16-sigma)

// ---------------- bucket build ----------------

__global__ void k_zero(int* __restrict__ a, int n) {
    int i = blockIdx.x * TPB + threadIdx.x;
    if (i < n) a[i] = 0;
}

// scatter each edge into its (stripe, dst-bucket) segment as (src<<5 | dstLocal).
// stripe = blockIdx&7 tracks the round-robin workgroup->XCD mapping, so each
// ebuf frontier line has a single-XCD writer -> ~1x writeback instead of ~12x.
__global__ void k_bfill(const int* __restrict__ src, const int* __restrict__ dst,
                        int* __restrict__ bcnt, unsigned* __restrict__ ebuf,
                        int nb, int E) {
    int e = blockIdx.x * TPB + threadIdx.x;
    if (e < E) {
        int d = dst[e];
        int seg = (blockIdx.x & (NSTRIPE - 1)) * nb + (d >> BSH);
        int pos = atomicAdd(&bcnt[seg], 1);      // int atomic: native HW RMW
        if (pos < SCAP) {
            unsigned pk = ((unsigned)src[e] << BSH) | (unsigned)(d & (BNODES - 1));
            ebuf[(size_t)seg * SCAP + pos] = pk;
        }
    }
}

// one WAVE per bucket: merge 8 stripe segments into LDS, int-LDS histogram,
// shfl-scan, scatter into padded CSR; emit deg / node_beg / dinv.
__global__ void k_bcsr(const int* __restrict__ bcnt, const unsigned* __restrict__ ebuf,
                       int* __restrict__ csr, int* __restrict__ node_beg,
                       int* __restrict__ degi, float* __restrict__ dinv, int nb, int n) {
    __shared__ unsigned se[4][CAP];        // 16 KB edge stage
    __shared__ int scnt[4][BNODES];
    __shared__ int sexc[4][BNODES];
    __shared__ int srnk[4][BNODES];
    int wv = threadIdx.x >> 6, lane = threadIdx.x & 63;
    int b = blockIdx.x * 4 + wv;
    bool act = (b < nb);
    if (lane < BNODES) { scnt[wv][lane] = 0; srnk[wv][lane] = 0; }
    __syncthreads();
    int cnt = 0;
    if (act) {
        for (int s = 0; s < NSTRIPE; ++s) {
            int c = bcnt[s * nb + b];
            if (c > SCAP) c = SCAP;
            if (cnt + c > CAP) c = CAP - cnt;
            const unsigned* p = &ebuf[(size_t)(s * nb + b) * SCAP];
            for (int k = lane; k < c; k += 64) {
                unsigned pk = p[k];
                se[wv][cnt + k] = pk;
                atomicAdd(&scnt[wv][pk & (BNODES - 1)], 1);   // int LDS atomic
            }
            cnt += c;
        }
    }
    __syncthreads();
    if (act && lane < BNODES) {
        int dg = scnt[wv][lane];
        int v = dg;
#pragma unroll
        for (int off = 1; off < BNODES; off <<= 1) {
            int t = __shfl_up(v, off, BNODES);
            if (lane >= off) v += t;
        }
        int excl = v - dg;
        sexc[wv][lane] = excl;
        int node = b * BNODES + lane;
        if (node < n) {
            degi[node] = dg;
            node_beg[node] = b * CAP + excl;
            dinv[node] = rsqrtf((float)dg + 1.0f);
        }
    }
    __syncthreads();
    if (act) {
        int* csrb = csr + (size_t)b * CAP;
        for (int k = lane; k < cnt; k += 64) {
            unsigned pk = se[wv][k];
            int dl = pk & (BNODES - 1);
            int r = atomicAdd(&srnk[wv][dl], 1);
            csrb[sexc[wv][dl] + r] = (int)(pk >> BSH);
        }
    }
}

// ---------------- dense transforms (pre-scaled by dinv[row], fp16 out) ------

// g[row,:] = fp16( dinv[row] * (x[row,:] @ W[64,64]) ); 4 rows/block
__global__ void k_xw64s(const float* __restrict__ x, const float* __restrict__ W,
                        const float* __restrict__ dinv, _Float16* __restrict__ g, int n) {
    __shared__ float Ws[64 * 64];
    __shared__ float xs[4][64];
    int tid = threadIdx.x;
    for (int i = tid; i < 64 * 64; i += TPB) Ws[i] = W[i];
    int r = tid >> 6, c = tid & 63;
    int row = blockIdx.x * 4 + r;
    if (row < n) xs[r][c] = x[(size_t)row * 64 + c];
    __syncthreads();
    if (row < n) {
        float acc = 0.f;
#pragma unroll
        for (int k = 0; k < 64; ++k) acc += xs[r][k] * Ws[k * 64 + c];
        g[(size_t)row * 64 + c] = (_Float16)(dinv[row] * acc);
    }
}

// g2[row,:19] = fp16( dinv[row] * (h[row,:] @ W2[64,19]) ); 8 rows/block; h fp16
__global__ void k_xw19s(const _Float16* __restrict__ h, const float* __restrict__ W,
                        const float* __restrict__ dinv, _Float16* __restrict__ g2, int n) {
    __shared__ float Ws[64][20];
    __shared__ float xs[8][64];
    int tid = threadIdx.x;
    for (int i = tid; i < 64 * 19; i += TPB) Ws[i / 19][i % 19] = W[i];
    for (int i = tid; i < 8 * 64; i += TPB) {
        int rr = i >> 6, cc = i & 63;
        int row = blockIdx.x * 8 + rr;
        if (row < n) xs[rr][cc] = (float)h[(size_t)row * 64 + cc];
    }
    __syncthreads();
    int r = tid >> 5, c = tid & 31;
    int row = blockIdx.x * 8 + r;
    if (row < n && c < 19) {
        float acc = 0.f;
#pragma unroll
        for (int k = 0; k < 64; ++k) acc += xs[r][k] * Ws[k][c];
        g2[(size_t)row * 19 + c] = (_Float16)(dinv[row] * acc);
    }
}

// ---------------- gather aggregation (register accumulate, no atomics) ------

// one wave per node; lane = (edge-slot e<<3) | feature-chunk f; each lane
// loads uint4 = 8 fp16 -> 8 edges per wave-iter, 16B/lane coalesced.
__global__ void k_gather64(const int* __restrict__ node_beg, const int* __restrict__ degi,
                           const int* __restrict__ csr, const float* __restrict__ dinv,
                           const _Float16* __restrict__ g, const float* __restrict__ b1,
                           _Float16* __restrict__ h, int n) {
    int node = blockIdx.x * 4 + (threadIdx.x >> 6);
    if (node >= n) return;
    int lane = threadIdx.x & 63;
    int eidx = lane >> 3, fch = lane & 7;
    int beg = node_beg[node], cnt = degi[node];
    float acc[8];
#pragma unroll
    for (int j = 0; j < 8; ++j) acc[j] = 0.f;
    for (int base = 0; base < cnt; base += 8) {
        int k = base + eidx;
        if (k < cnt) {
            int row = csr[beg + k];
            uint4 v = *((const uint4*)(g + (size_t)row * 64) + fch);
            const _Float16* f = (const _Float16*)&v;
#pragma unroll
            for (int j = 0; j < 8; ++j) acc[j] += (float)f[j];
        }
    }
#pragma unroll
    for (int m = 8; m < 64; m <<= 1) {
#pragma unroll
        for (int j = 0; j < 8; ++j) acc[j] += __shfl_xor(acc[j], m);
    }
    if (eidx == 0) {   // lanes 0-7 hold chunks 0-7
        uint4 v = *((const uint4*)(g + (size_t)node * 64) + fch);   // self-loop
        const _Float16* f = (const _Float16*)&v;
        float dv = dinv[node];
        _Float16 outv[8];
#pragma unroll
        for (int j = 0; j < 8; ++j) {
            float val = dv * (acc[j] + (float)f[j]) + b1[fch * 8 + j];
            outv[j] = (_Float16)fmaxf(val, 0.f);
        }
        *((uint4*)(h + (size_t)node * 64) + fch) = *(const uint4*)outv;
    }
}

// out[d,c] = dinv[d]*(g2[d,c] + sum g2[s,c]) + b2[c]; 32 lanes/node (19 active)
__global__ void k_gather19(const int* __restrict__ node_beg, const int* __restrict__ degi,
                           const int* __restrict__ csr, const float* __restrict__ dinv,
                           const _Float16* __restrict__ g2, const float* __restrict__ b2,
                           float* __restrict__ out, int n) {
    int node = blockIdx.x * 8 + (threadIdx.x >> 5);
    if (node >= n) return;
    int c = threadIdx.x & 31;
    if (c >= 19) return;
    int beg = node_beg[node], cnt = degi[node];
    float a0 = (float)g2[(size_t)node * 19 + c];     // self-loop
    float a1 = 0.f, a2 = 0.f, a3 = 0.f;
    int k = 0;
    for (; k + 3 < cnt; k += 4) {
        int s0 = csr[beg + k];
        int s1 = csr[beg + k + 1];
        int s2 = csr[beg + k + 2];
        int s3 = csr[beg + k + 3];
        a0 += (float)g2[(size_t)s0 * 19 + c];
        a1 += (float)g2[(size_t)s1 * 19 + c];
        a2 += (float)g2[(size_t)s2 * 19 + c];
        a3 += (float)g2[(size_t)s3 * 19 + c];
    }
    for (; k < cnt; ++k) a1 += (float)g2[(size_t)csr[beg + k] * 19 + c];
    out[(size_t)node * 19 + c] = dinv[node] * ((a0 + a1) + (a2 + a3)) + b2[c];
}

// ---------------- launch ----------------

extern "C" void kernel_launch(void* const* d_in, const int* in_sizes, int n_in,
                              void* d_out, int out_size, void* d_ws, size_t ws_size,
                              hipStream_t stream) {
    const float* x  = (const float*)d_in[0];
    const int*   ei = (const int*)d_in[1];
    const float* W1 = (const float*)d_in[2];
    const float* b1 = (const float*)d_in[3];
    const float* W2 = (const float*)d_in[4];
    const float* b2 = (const float*)d_in[5];
    float* out = (float*)d_out;

    int N = in_sizes[0] / 64;
    int E = in_sizes[1] / 2;
    const int* src = ei;
    const int* dst = ei + E;

    int NB = (N + BNODES - 1) >> BSH;   // 3125 for N=100000
    int NSEG = NSTRIPE * NB;

    char* w = (char*)d_ws;
    int* bcnt      = (int*)w;      w += (size_t)NSEG * 4;
    int* degi      = (int*)w;      w += (size_t)N * 4;
    int* node_beg  = (int*)w;      w += (size_t)N * 4;
    float* dinv    = (float*)w;    w += (size_t)N * 4;
    w = (char*)(((size_t)w + 63) & ~(size_t)63);
    unsigned* ebuf = (unsigned*)w; w += (size_t)NSEG * SCAP * 4;   // 19.2 MB
    int* csr       = (int*)w;      w += (size_t)NB * CAP * 4;      // 12.8 MB
    _Float16* g1   = (_Float16*)w; w += (size_t)N * 64 * 2;
    _Float16* h    = (_Float16*)w; w += (size_t)N * 64 * 2;
    _Float16* g2   = g1;  // g1 dead after k_gather64; reuse

    int gE = (E + TPB - 1) / TPB;

    k_zero    <<<(NSEG + TPB - 1) / TPB, TPB, 0, stream>>>(bcnt, NSEG);
    k_bfill   <<<gE, TPB, 0, stream>>>(src, dst, bcnt, ebuf, NB, E);
    k_bcsr    <<<(NB + 3) / 4, TPB, 0, stream>>>(bcnt, ebuf, csr, node_beg, degi, dinv, NB, N);

    k_xw64s   <<<(N + 3) / 4, TPB, 0, stream>>>(x, W1, dinv, g1, N);
    k_gather64<<<(N + 3) / 4, TPB, 0, stream>>>(node_beg, degi, csr, dinv, g1, b1, h, N);

    k_xw19s   <<<(N + 7) / 8, TPB, 0, stream>>>(h, W2, dinv, g2, N);
    k_gather19<<<(N + 7) / 8, TPB, 0, stream>>>(node_beg, degi, csr, dinv, g2, b2, out, N);
}

// Round 8
// 230.920 us; speedup vs baseline: 4.1195x; 1.1237x over previous
//
#include <hip/hip_runtime.h>

#define TPB 256
#define BSH 5                    // 32 dst nodes per bucket
#define BNODES 32
#define CAP 1024                 // slots per bucket region (mean load 512)
#define EPB 4096                 // edges per partition block
#define NBMAX 3200               // LDS counter array bound (nb = 3125)

// ---------------- deterministic bucket partition (counting sort) ------------

// pass 1: per-block bucket histogram via LDS int atomics; clean row write
__global__ void k_hist1(const int* __restrict__ dst, int* __restrict__ hist,
                        int nb, int E) {
    __shared__ int sh[NBMAX];
    int tid = threadIdx.x, blk = blockIdx.x;
    for (int i = tid; i < nb; i += TPB) sh[i] = 0;
    __syncthreads();
    int e0 = blk * EPB;
    for (int i = tid; i < EPB; i += TPB) {
        int e = e0 + i;
        if (e < E) atomicAdd(&sh[dst[e] >> BSH], 1);
    }
    __syncthreads();
    int* hrow = hist + (size_t)blk * nb;
    for (int i = tid; i < nb; i += TPB) hrow[i] = sh[i];
}

// pass 2: per-bucket slot offsets in STRIPE-GROUPED block order (blocks
// q*8+s grouped by s), so adjacent ranges in a bucket belong to same-XCD
// blocks -> single-L2 writer per line in pass 3. 8 lanes per bucket.
__global__ void k_scanoff(const int* __restrict__ hist, int* __restrict__ offs,
                          int* __restrict__ bcnt, int nblk, int nb) {
    int t = blockIdx.x * TPB + threadIdx.x;
    int b = t >> 3, s = t & 7;
    if (b >= nb) return;
    int nps = (nblk + 7) >> 3;
    int sum = 0;
    for (int q = 0; q < nps; ++q) {
        int blk = q * 8 + s;
        if (blk < nblk) sum += hist[(size_t)blk * nb + b];
    }
    int v = sum;
#pragma unroll
    for (int o = 1; o < 8; o <<= 1) {
        int u = __shfl_up(v, o, 8);
        if (s >= o) v += u;
    }
    int total = __shfl(v, 7, 8);
    if (s == 0) bcnt[b] = total;
    int off = b * CAP + (v - sum);   // exclusive within bucket, stripe-grouped
    for (int q = 0; q < nps; ++q) {
        int blk = q * 8 + s;
        if (blk < nblk) {
            offs[(size_t)blk * nb + b] = off;
            off += hist[(size_t)blk * nb + b];
        }
    }
}

// pass 3: scatter edges to exact slots; LDS cursors, ZERO global atomics
__global__ void k_scatter(const int* __restrict__ src, const int* __restrict__ dst,
                          const int* __restrict__ offs, unsigned* __restrict__ ebuf,
                          int nb, int E) {
    __shared__ int cur[NBMAX];
    int tid = threadIdx.x, blk = blockIdx.x;
    const int* orow = offs + (size_t)blk * nb;
    for (int i = tid; i < nb; i += TPB) cur[i] = orow[i];
    __syncthreads();
    int e0 = blk * EPB;
    for (int i = tid; i < EPB; i += TPB) {
        int e = e0 + i;
        if (e < E) {
            int d = dst[e];
            int pos = atomicAdd(&cur[d >> BSH], 1);   // int LDS atomic: native
            ebuf[pos] = ((unsigned)src[e] << BSH) | (unsigned)(d & (BNODES - 1));
        }
    }
}

// one WAVE per bucket: stage edges, int-LDS histogram, shfl-scan,
// scatter into padded per-node CSR; emit deg / node_beg / dinv.
__global__ void k_bcsr(const int* __restrict__ bcnt, const unsigned* __restrict__ ebuf,
                       int* __restrict__ csr, int* __restrict__ node_beg,
                       int* __restrict__ degi, float* __restrict__ dinv, int nb, int n) {
    __shared__ unsigned se[4][CAP];        // 16 KB edge stage
    __shared__ int scnt[4][BNODES];
    __shared__ int sexc[4][BNODES];
    __shared__ int srnk[4][BNODES];
    int wv = threadIdx.x >> 6, lane = threadIdx.x & 63;
    int b = blockIdx.x * 4 + wv;
    bool act = (b < nb);
    if (lane < BNODES) { scnt[wv][lane] = 0; srnk[wv][lane] = 0; }
    __syncthreads();
    int cnt = 0;
    if (act) {
        cnt = bcnt[b];
        if (cnt > CAP) cnt = CAP;
        const unsigned* p = &ebuf[(size_t)b * CAP];
        for (int k = lane; k < cnt; k += 64) {
            unsigned pk = p[k];
            se[wv][k] = pk;
            atomicAdd(&scnt[wv][pk & (BNODES - 1)], 1);   // int LDS atomic
        }
    }
    __syncthreads();
    if (act && lane < BNODES) {
        int dg = scnt[wv][lane];
        int v = dg;
#pragma unroll
        for (int off = 1; off < BNODES; off <<= 1) {
            int t = __shfl_up(v, off, BNODES);
            if (lane >= off) v += t;
        }
        int excl = v - dg;
        sexc[wv][lane] = excl;
        int node = b * BNODES + lane;
        if (node < n) {
            degi[node] = dg;
            node_beg[node] = b * CAP + excl;
            dinv[node] = rsqrtf((float)dg + 1.0f);
        }
    }
    __syncthreads();
    if (act) {
        int* csrb = csr + (size_t)b * CAP;
        for (int k = lane; k < cnt; k += 64) {
            unsigned pk = se[wv][k];
            int dl = pk & (BNODES - 1);
            int r = atomicAdd(&srnk[wv][dl], 1);
            csrb[sexc[wv][dl] + r] = (int)(pk >> BSH);
        }
    }
}

// ---------------- dense transforms (pre-scaled by dinv[row], fp16 out) ------

// g[row,:] = fp16( dinv[row] * (x[row,:] @ W[64,64]) ); 4 rows/block
__global__ void k_xw64s(const float* __restrict__ x, const float* __restrict__ W,
                        const float* __restrict__ dinv, _Float16* __restrict__ g, int n) {
    __shared__ float Ws[64 * 64];
    __shared__ float xs[4][64];
    int tid = threadIdx.x;
    for (int i = tid; i < 64 * 64; i += TPB) Ws[i] = W[i];
    int r = tid >> 6, c = tid & 63;
    int row = blockIdx.x * 4 + r;
    if (row < n) xs[r][c] = x[(size_t)row * 64 + c];
    __syncthreads();
    if (row < n) {
        float acc = 0.f;
#pragma unroll
        for (int k = 0; k < 64; ++k) acc += xs[r][k] * Ws[k * 64 + c];
        g[(size_t)row * 64 + c] = (_Float16)(dinv[row] * acc);
    }
}

// g2[row,:19] = fp16( dinv[row] * (h[row,:] @ W2[64,19]) ); 8 rows/block; h fp16
__global__ void k_xw19s(const _Float16* __restrict__ h, const float* __restrict__ W,
                        const float* __restrict__ dinv, _Float16* __restrict__ g2, int n) {
    __shared__ float Ws[64][20];
    __shared__ float xs[8][64];
    int tid = threadIdx.x;
    for (int i = tid; i < 64 * 19; i += TPB) Ws[i / 19][i % 19] = W[i];
    for (int i = tid; i < 8 * 64; i += TPB) {
        int rr = i >> 6, cc = i & 63;
        int row = blockIdx.x * 8 + rr;
        if (row < n) xs[rr][cc] = (float)h[(size_t)row * 64 + cc];
    }
    __syncthreads();
    int r = tid >> 5, c = tid & 31;
    int row = blockIdx.x * 8 + r;
    if (row < n && c < 19) {
        float acc = 0.f;
#pragma unroll
        for (int k = 0; k < 64; ++k) acc += xs[r][k] * Ws[k][c];
        g2[(size_t)row * 19 + c] = (_Float16)(dinv[row] * acc);
    }
}

// ---------------- gather aggregation (register accumulate, no atomics) ------

// one wave per node; lane = (edge-slot e<<3) | feature-chunk f; each lane
// loads uint4 = 8 fp16 -> 8 edges per wave-iter, 16B/lane coalesced.
__global__ void k_gather64(const int* __restrict__ node_beg, const int* __restrict__ degi,
                           const int* __restrict__ csr, const float* __restrict__ dinv,
                           const _Float16* __restrict__ g, const float* __restrict__ b1,
                           _Float16* __restrict__ h, int n) {
    int node = blockIdx.x * 4 + (threadIdx.x >> 6);
    if (node >= n) return;
    int lane = threadIdx.x & 63;
    int eidx = lane >> 3, fch = lane & 7;
    int beg = node_beg[node], cnt = degi[node];
    float acc[8];
#pragma unroll
    for (int j = 0; j < 8; ++j) acc[j] = 0.f;
    for (int base = 0; base < cnt; base += 8) {
        int k = base + eidx;
        if (k < cnt) {
            int row = csr[beg + k];
            uint4 v = *((const uint4*)(g + (size_t)row * 64) + fch);
            const _Float16* f = (const _Float16*)&v;
#pragma unroll
            for (int j = 0; j < 8; ++j) acc[j] += (float)f[j];
        }
    }
#pragma unroll
    for (int m = 8; m < 64; m <<= 1) {
#pragma unroll
        for (int j = 0; j < 8; ++j) acc[j] += __shfl_xor(acc[j], m);
    }
    if (eidx == 0) {   // lanes 0-7 hold chunks 0-7
        uint4 v = *((const uint4*)(g + (size_t)node * 64) + fch);   // self-loop
        const _Float16* f = (const _Float16*)&v;
        float dv = dinv[node];
        _Float16 outv[8];
#pragma unroll
        for (int j = 0; j < 8; ++j) {
            float val = dv * (acc[j] + (float)f[j]) + b1[fch * 8 + j];
            outv[j] = (_Float16)fmaxf(val, 0.f);
        }
        *((uint4*)(h + (size_t)node * 64) + fch) = *(const uint4*)outv;
    }
}

// out[d,c] = dinv[d]*(g2[d,c] + sum g2[s,c]) + b2[c]; 32 lanes/node (19 active)
__global__ void k_gather19(const int* __restrict__ node_beg, const int* __restrict__ degi,
                           const int* __restrict__ csr, const float* __restrict__ dinv,
                           const _Float16* __restrict__ g2, const float* __restrict__ b2,
                           float* __restrict__ out, int n) {
    int node = blockIdx.x * 8 + (threadIdx.x >> 5);
    if (node >= n) return;
    int c = threadIdx.x & 31;
    if (c >= 19) return;
    int beg = node_beg[node], cnt = degi[node];
    float a0 = (float)g2[(size_t)node * 19 + c];     // self-loop
    float a1 = 0.f, a2 = 0.f, a3 = 0.f;
    int k = 0;
    for (; k + 3 < cnt; k += 4) {
        int s0 = csr[beg + k];
        int s1 = csr[beg + k + 1];
        int s2 = csr[beg + k + 2];
        int s3 = csr[beg + k + 3];
        a0 += (float)g2[(size_t)s0 * 19 + c];
        a1 += (float)g2[(size_t)s1 * 19 + c];
        a2 += (float)g2[(size_t)s2 * 19 + c];
        a3 += (float)g2[(size_t)s3 * 19 + c];
    }
    for (; k < cnt; ++k) a1 += (float)g2[(size_t)csr[beg + k] * 19 + c];
    out[(size_t)node * 19 + c] = dinv[node] * ((a0 + a1) + (a2 + a3)) + b2[c];
}

// ---------------- launch ----------------

extern "C" void kernel_launch(void* const* d_in, const int* in_sizes, int n_in,
                              void* d_out, int out_size, void* d_ws, size_t ws_size,
                              hipStream_t stream) {
    const float* x  = (const float*)d_in[0];
    const int*   ei = (const int*)d_in[1];
    const float* W1 = (const float*)d_in[2];
    const float* b1 = (const float*)d_in[3];
    const float* W2 = (const float*)d_in[4];
    const float* b2 = (const float*)d_in[5];
    float* out = (float*)d_out;

    int N = in_sizes[0] / 64;
    int E = in_sizes[1] / 2;
    const int* src = ei;
    const int* dst = ei + E;

    int NB = (N + BNODES - 1) >> BSH;        // 3125 for N=100000
    int NBLK = (E + EPB - 1) / EPB;          // 391 for E=1.6M

    char* w = (char*)d_ws;
    int* bcnt      = (int*)w;      w += (size_t)NB * 4;
    int* degi      = (int*)w;      w += (size_t)N * 4;
    int* node_beg  = (int*)w;      w += (size_t)N * 4;
    float* dinv    = (float*)w;    w += (size_t)N * 4;
    w = (char*)(((size_t)w + 63) & ~(size_t)63);
    // region A: hist+offs (build passes), later reused as csr (bcsr onward)
    char* regionA  = w;
    size_t histB   = (size_t)NBLK * NB * 4;                  // 4.9 MB
    size_t csrB    = (size_t)NB * CAP * 4;                   // 12.8 MB
    size_t regA    = (histB * 2 > csrB) ? histB * 2 : csrB;
    int* hist      = (int*)regionA;
    int* offs      = (int*)(regionA + histB);
    int* csr       = (int*)regionA;          // alias: hist/offs dead by k_bcsr
    w += regA;
    unsigned* ebuf = (unsigned*)w; w += (size_t)NB * CAP * 4;
    _Float16* g1   = (_Float16*)w; w += (size_t)N * 64 * 2;
    _Float16* h    = (_Float16*)w; w += (size_t)N * 64 * 2;
    _Float16* g2   = g1;  // g1 dead after k_gather64; reuse

    k_hist1   <<<NBLK, TPB, 0, stream>>>(dst, hist, NB, E);
    k_scanoff <<<(NB * 8 + TPB - 1) / TPB, TPB, 0, stream>>>(hist, offs, bcnt, NBLK, NB);
    k_scatter <<<NBLK, TPB, 0, stream>>>(src, dst, offs, ebuf, NB, E);
    k_bcsr    <<<(NB + 3) / 4, TPB, 0, stream>>>(bcnt, ebuf, csr, node_beg, degi, dinv, NB, N);

    k_xw64s   <<<(N + 3) / 4, TPB, 0, stream>>>(x, W1, dinv, g1, N);
    k_gather64<<<(N + 3) / 4, TPB, 0, stream>>>(node_beg, degi, csr, dinv, g1, b1, h, N);

    k_xw19s   <<<(N + 7) / 8, TPB, 0, stream>>>(h, W2, dinv, g2, N);
    k_gather19<<<(N + 7) / 8, TPB, 0, stream>>>(node_beg, degi, csr, dinv, g2, b2, out, N);
}

// Round 9
// 223.929 us; speedup vs baseline: 4.2481x; 1.0312x over previous
//
#include <hip/hip_runtime.h>

#define TPB 256
#define BSH 5                    // 32 dst nodes per bucket
#define BNODES 32
#define CAP 1024                 // slots per bucket region (mean load 512)
#define EPB 4096                 // edges per partition block
#define NBMAX 3200               // LDS counter array bound (nb = 3125)

// ---------------- deterministic bucket partition (counting sort) ------------

// pass 1: per-block bucket histogram via LDS int atomics; clean row write
__global__ void k_hist1(const int* __restrict__ dst, int* __restrict__ hist,
                        int nb, int E) {
    __shared__ int sh[NBMAX];
    int tid = threadIdx.x, blk = blockIdx.x;
    for (int i = tid; i < nb; i += TPB) sh[i] = 0;
    __syncthreads();
    int e0 = blk * EPB;
    for (int i = tid; i < EPB; i += TPB) {
        int e = e0 + i;
        if (e < E) atomicAdd(&sh[dst[e] >> BSH], 1);
    }
    __syncthreads();
    int* hrow = hist + (size_t)blk * nb;
    for (int i = tid; i < nb; i += TPB) hrow[i] = sh[i];
}

// pass 2: per-bucket slot offsets in STRIPE-GROUPED block order
__global__ void k_scanoff(const int* __restrict__ hist, int* __restrict__ offs,
                          int* __restrict__ bcnt, int nblk, int nb) {
    int t = blockIdx.x * TPB + threadIdx.x;
    int b = t >> 3, s = t & 7;
    if (b >= nb) return;
    int nps = (nblk + 7) >> 3;
    int sum = 0;
    for (int q = 0; q < nps; ++q) {
        int blk = q * 8 + s;
        if (blk < nblk) sum += hist[(size_t)blk * nb + b];
    }
    int v = sum;
#pragma unroll
    for (int o = 1; o < 8; o <<= 1) {
        int u = __shfl_up(v, o, 8);
        if (s >= o) v += u;
    }
    int total = __shfl(v, 7, 8);
    if (s == 0) bcnt[b] = total;
    int off = b * CAP + (v - sum);   // exclusive within bucket, stripe-grouped
    for (int q = 0; q < nps; ++q) {
        int blk = q * 8 + s;
        if (blk < nblk) {
            offs[(size_t)blk * nb + b] = off;
            off += hist[(size_t)blk * nb + b];
        }
    }
}

// pass 3: scatter edges to exact slots; LDS cursors, ZERO global atomics
__global__ void k_scatter(const int* __restrict__ src, const int* __restrict__ dst,
                          const int* __restrict__ offs, unsigned* __restrict__ ebuf,
                          int nb, int E) {
    __shared__ int cur[NBMAX];
    int tid = threadIdx.x, blk = blockIdx.x;
    const int* orow = offs + (size_t)blk * nb;
    for (int i = tid; i < nb; i += TPB) cur[i] = orow[i];
    __syncthreads();
    int e0 = blk * EPB;
    for (int i = tid; i < EPB; i += TPB) {
        int e = e0 + i;
        if (e < E) {
            int d = dst[e];
            int pos = atomicAdd(&cur[d >> BSH], 1);   // int LDS atomic: native
            ebuf[pos] = ((unsigned)src[e] << BSH) | (unsigned)(d & (BNODES - 1));
        }
    }
}

// one WAVE per bucket: stage edges, int-LDS histogram, shfl-scan,
// scatter into padded per-node CSR; emit deg / node_beg / dinv.
__global__ void k_bcsr(const int* __restrict__ bcnt, const unsigned* __restrict__ ebuf,
                       int* __restrict__ csr, int* __restrict__ node_beg,
                       int* __restrict__ degi, float* __restrict__ dinv, int nb, int n) {
    __shared__ unsigned se[4][CAP];        // 16 KB edge stage
    __shared__ int scnt[4][BNODES];
    __shared__ int sexc[4][BNODES];
    __shared__ int srnk[4][BNODES];
    int wv = threadIdx.x >> 6, lane = threadIdx.x & 63;
    int b = blockIdx.x * 4 + wv;
    bool act = (b < nb);
    if (lane < BNODES) { scnt[wv][lane] = 0; srnk[wv][lane] = 0; }
    __syncthreads();
    int cnt = 0;
    if (act) {
        cnt = bcnt[b];
        if (cnt > CAP) cnt = CAP;
        const unsigned* p = &ebuf[(size_t)b * CAP];
        for (int k = lane; k < cnt; k += 64) {
            unsigned pk = p[k];
            se[wv][k] = pk;
            atomicAdd(&scnt[wv][pk & (BNODES - 1)], 1);   // int LDS atomic
        }
    }
    __syncthreads();
    if (act && lane < BNODES) {
        int dg = scnt[wv][lane];
        int v = dg;
#pragma unroll
        for (int off = 1; off < BNODES; off <<= 1) {
            int t = __shfl_up(v, off, BNODES);
            if (lane >= off) v += t;
        }
        int excl = v - dg;
        sexc[wv][lane] = excl;
        int node = b * BNODES + lane;
        if (node < n) {
            degi[node] = dg;
            node_beg[node] = b * CAP + excl;
            dinv[node] = rsqrtf((float)dg + 1.0f);
        }
    }
    __syncthreads();
    if (act) {
        int* csrb = csr + (size_t)b * CAP;
        for (int k = lane; k < cnt; k += 64) {
            unsigned pk = se[wv][k];
            int dl = pk & (BNODES - 1);
            int r = atomicAdd(&srnk[wv][dl], 1);
            csrb[sexc[wv][dl] + r] = (int)(pk >> BSH);
        }
    }
}

// ---------------- dense transforms (register-blocked tile GEMM) -------------

// g[row,:] = fp16(dinv[row]*(x[row,:]@W1)); 64 rows/block, 4x4 acc per thread
__global__ void k_xw64v(const float* __restrict__ x, const float* __restrict__ W,
                        const float* __restrict__ dinv, _Float16* __restrict__ g, int n) {
    __shared__ float Ws[64 * 64];    // [k][c]
    __shared__ float xsT[64 * 64];   // [k][row_local]
    int tid = threadIdx.x;
    int row0 = blockIdx.x * 64;
    for (int i = tid; i < 1024; i += TPB)
        reinterpret_cast<float4*>(Ws)[i] = reinterpret_cast<const float4*>(W)[i];
    {
        int rl = tid >> 2, cq = (tid & 3) * 16;
        int row = row0 + rl;
#pragma unroll
        for (int j4 = 0; j4 < 4; ++j4) {
            float4 v = make_float4(0.f, 0.f, 0.f, 0.f);
            if (row < n) v = *reinterpret_cast<const float4*>(x + (size_t)row * 64 + cq + j4 * 4);
            xsT[(cq + j4 * 4 + 0) * 64 + rl] = v.x;
            xsT[(cq + j4 * 4 + 1) * 64 + rl] = v.y;
            xsT[(cq + j4 * 4 + 2) * 64 + rl] = v.z;
            xsT[(cq + j4 * 4 + 3) * 64 + rl] = v.w;
        }
    }
    __syncthreads();
    int c4 = (tid & 15) * 4, rq = (tid >> 4) * 4;
    float acc[4][4] = {};
#pragma unroll 4
    for (int k = 0; k < 64; ++k) {
        float4 wv = *reinterpret_cast<const float4*>(Ws + k * 64 + c4);
        float4 xv = *reinterpret_cast<const float4*>(xsT + k * 64 + rq);
        const float* wp = (const float*)&wv;
        const float* xp = (const float*)&xv;
#pragma unroll
        for (int i = 0; i < 4; ++i)
#pragma unroll
            for (int j = 0; j < 4; ++j) acc[i][j] += xp[i] * wp[j];
    }
#pragma unroll
    for (int i = 0; i < 4; ++i) {
        int row = row0 + rq + i;
        if (row < n) {
            float dv = dinv[row];
            _Float16 o[4];
#pragma unroll
            for (int j = 0; j < 4; ++j) o[j] = (_Float16)(dv * acc[i][j]);
            *reinterpret_cast<ushort4*>(g + (size_t)row * 64 + c4) =
                *reinterpret_cast<const ushort4*>(o);
        }
    }
}

// g2p[row,0:32] = fp16(dinv[row]*(h[row,:]@W2)) padded to 32 cols (19 valid);
// 32 rows/block, 4 rows/thread
__global__ void k_xw19v(const _Float16* __restrict__ h, const float* __restrict__ W,
                        const float* __restrict__ dinv, _Float16* __restrict__ g2p, int n) {
    __shared__ float Ws[64 * 32];    // [k][c], c>=19 zero
    __shared__ float xsT[64 * 32];   // [k][row_local]
    int tid = threadIdx.x;
    int row0 = blockIdx.x * 32;
    for (int i = tid; i < 64 * 32; i += TPB) {
        int k = i >> 5, c = i & 31;
        Ws[i] = (c < 19) ? W[k * 19 + c] : 0.f;
    }
    {
        int rl = tid >> 3, sq = tid & 7;
        int row = row0 + rl;
        if (row < n) {
            uint4 v = *(reinterpret_cast<const uint4*>(h + (size_t)row * 64) + sq);
            const _Float16* f = (const _Float16*)&v;
#pragma unroll
            for (int j = 0; j < 8; ++j) xsT[(sq * 8 + j) * 32 + rl] = (float)f[j];
        } else {
#pragma unroll
            for (int j = 0; j < 8; ++j) xsT[(sq * 8 + j) * 32 + rl] = 0.f;
        }
    }
    __syncthreads();
    int c = tid & 31, rg = (tid >> 5) * 4;
    float acc[4] = {};
#pragma unroll 4
    for (int k = 0; k < 64; ++k) {
        float wv = Ws[k * 32 + c];
        float4 xv = *reinterpret_cast<const float4*>(xsT + k * 32 + rg);
        const float* xp = (const float*)&xv;
#pragma unroll
        for (int i = 0; i < 4; ++i) acc[i] += xp[i] * wv;
    }
#pragma unroll
    for (int i = 0; i < 4; ++i) {
        int row = row0 + rg + i;
        if (row < n)
            g2p[(size_t)row * 32 + c] = (c < 19) ? (_Float16)(dinv[row] * acc[i])
                                                 : (_Float16)0.f;
    }
}

// ---------------- gather aggregation (register accumulate, no atomics) ------

// one wave per node; lane = (edge-slot<<3)|feature-chunk; uint4 = 8 fp16/lane
__global__ void k_gather64(const int* __restrict__ node_beg, const int* __restrict__ degi,
                           const int* __restrict__ csr, const float* __restrict__ dinv,
                           const _Float16* __restrict__ g, const float* __restrict__ b1,
                           _Float16* __restrict__ h, int n) {
    int node = blockIdx.x * 4 + (threadIdx.x >> 6);
    if (node >= n) return;
    int lane = threadIdx.x & 63;
    int eidx = lane >> 3, fch = lane & 7;
    int beg = node_beg[node], cnt = degi[node];
    float acc[8];
#pragma unroll
    for (int j = 0; j < 8; ++j) acc[j] = 0.f;
    for (int base = 0; base < cnt; base += 8) {
        int k = base + eidx;
        if (k < cnt) {
            int row = csr[beg + k];
            uint4 v = *((const uint4*)(g + (size_t)row * 64) + fch);
            const _Float16* f = (const _Float16*)&v;
#pragma unroll
            for (int j = 0; j < 8; ++j) acc[j] += (float)f[j];
        }
    }
#pragma unroll
    for (int m = 8; m < 64; m <<= 1) {
#pragma unroll
        for (int j = 0; j < 8; ++j) acc[j] += __shfl_xor(acc[j], m);
    }
    if (eidx == 0) {   // lanes 0-7 hold chunks 0-7
        uint4 v = *((const uint4*)(g + (size_t)node * 64) + fch);   // self-loop
        const _Float16* f = (const _Float16*)&v;
        float dv = dinv[node];
        _Float16 outv[8];
#pragma unroll
        for (int j = 0; j < 8; ++j) {
            float val = dv * (acc[j] + (float)f[j]) + b1[fch * 8 + j];
            outv[j] = (_Float16)fmaxf(val, 0.f);
        }
        *((uint4*)(h + (size_t)node * 64) + fch) = *(const uint4*)outv;
    }
}

// one wave per node; lane = (eidx<<2)|fq; uint4 = 8 fp16 of padded g2p row
__global__ void k_gath19(const int* __restrict__ node_beg, const int* __restrict__ degi,
                         const int* __restrict__ csr, const float* __restrict__ dinv,
                         const _Float16* __restrict__ g2p, const float* __restrict__ b2,
                         float* __restrict__ out, int n) {
    int node = blockIdx.x * 4 + (threadIdx.x >> 6);
    if (node >= n) return;
    int lane = threadIdx.x & 63;
    int eidx = lane >> 2, fq = lane & 3;
    int beg = node_beg[node], cnt = degi[node];
    float acc[8];
#pragma unroll
    for (int j = 0; j < 8; ++j) acc[j] = 0.f;
    for (int base = 0; base < cnt; base += 16) {
        int k = base + eidx;
        if (k < cnt) {
            int row = csr[beg + k];
            uint4 v = *((const uint4*)(g2p + (size_t)row * 32) + fq);
            const _Float16* f = (const _Float16*)&v;
#pragma unroll
            for (int j = 0; j < 8; ++j) acc[j] += (float)f[j];
        }
    }
    if (eidx == 0) {   // self-loop, counted once
        uint4 v = *((const uint4*)(g2p + (size_t)node * 32) + fq);
        const _Float16* f = (const _Float16*)&v;
#pragma unroll
        for (int j = 0; j < 8; ++j) acc[j] += (float)f[j];
    }
#pragma unroll
    for (int m = 4; m < 64; m <<= 1) {
#pragma unroll
        for (int j = 0; j < 8; ++j) acc[j] += __shfl_xor(acc[j], m);
    }
    if (eidx == 0) {
        float dv = dinv[node];
#pragma unroll
        for (int j = 0; j < 8; ++j) {
            int cc = fq * 8 + j;
            if (cc < 19) out[(size_t)node * 19 + cc] = dv * acc[j] + b2[cc];
        }
    }
}

// ---------------- launch ----------------

extern "C" void kernel_launch(void* const* d_in, const int* in_sizes, int n_in,
                              void* d_out, int out_size, void* d_ws, size_t ws_size,
                              hipStream_t stream) {
    const float* x  = (const float*)d_in[0];
    const int*   ei = (const int*)d_in[1];
    const float* W1 = (const float*)d_in[2];
    const float* b1 = (const float*)d_in[3];
    const float* W2 = (const float*)d_in[4];
    const float* b2 = (const float*)d_in[5];
    float* out = (float*)d_out;

    int N = in_sizes[0] / 64;
    int E = in_sizes[1] / 2;
    const int* src = ei;
    const int* dst = ei + E;

    int NB = (N + BNODES - 1) >> BSH;        // 3125 for N=100000
    int NBLK = (E + EPB - 1) / EPB;          // 391 for E=1.6M

    char* w = (char*)d_ws;
    int* bcnt      = (int*)w;      w += (size_t)NB * 4;
    int* degi      = (int*)w;      w += (size_t)N * 4;
    int* node_beg  = (int*)w;      w += (size_t)N * 4;
    float* dinv    = (float*)w;    w += (size_t)N * 4;
    w = (char*)(((size_t)w + 63) & ~(size_t)63);
    // region A: hist+offs (build passes), later reused as csr (bcsr onward)
    char* regionA  = w;
    size_t histB   = (size_t)NBLK * NB * 4;                  // 4.9 MB
    size_t csrB    = (size_t)NB * CAP * 4;                   // 12.8 MB
    size_t regA    = (histB * 2 > csrB) ? histB * 2 : csrB;
    int* hist      = (int*)regionA;
    int* offs      = (int*)(regionA + histB);
    int* csr       = (int*)regionA;          // alias: hist/offs dead by k_bcsr
    w += regA;
    unsigned* ebuf = (unsigned*)w; w += (size_t)NB * CAP * 4;
    _Float16* g1   = (_Float16*)w; w += (size_t)N * 64 * 2;
    _Float16* h    = (_Float16*)w; w += (size_t)N * 64 * 2;
    _Float16* g2p  = g1;  // g1 (N*64*2 B) dead after k_gather64; reuse (N*32*2 B)

    k_hist1   <<<NBLK, TPB, 0, stream>>>(dst, hist, NB, E);
    k_scanoff <<<(NB * 8 + TPB - 1) / TPB, TPB, 0, stream>>>(hist, offs, bcnt, NBLK, NB);
    k_scatter <<<NBLK, TPB, 0, stream>>>(src, dst, offs, ebuf, NB, E);
    k_bcsr    <<<(NB + 3) / 4, TPB, 0, stream>>>(bcnt, ebuf, csr, node_beg, degi, dinv, NB, N);

    k_xw64v   <<<(N + 63) / 64, TPB, 0, stream>>>(x, W1, dinv, g1, N);
    k_gather64<<<(N + 3) / 4, TPB, 0, stream>>>(node_beg, degi, csr, dinv, g1, b1, h, N);

    k_xw19v   <<<(N + 31) / 32, TPB, 0, stream>>>(h, W2, dinv, g2p, N);
    k_gath19  <<<(N + 3) / 4, TPB, 0, stream>>>(node_beg, degi, csr, dinv, g2p, b2, out, N);
}